// Round 1
// baseline (194.282 us; speedup 1.0000x reference)
//
#include <hip/hip_runtime.h>

// Gate / MoE router: logits = x @ W^T, softmax over E=8, top-2, renormalize.
// x: [T=16384, D=2048] fp32, W: [E=8, D=2048] fp32.
// out: [T*2] routing weights (fp32) followed by [T*2] expert indices (as fp32).
//
// Renormalized top-2 softmax simplifies: w1 = 1/(1+exp(l2-l1)), w2 = 1-w1
// (full softmax denominator cancels), so no full softmax needed.

constexpr int D = 2048;
constexpr int E = 8;
constexpr int NT = 16384;
constexpr int T_PER_WAVE = 4;       // tokens per wave
constexpr int WAVES_PER_BLOCK = 4;  // 256-thread blocks
constexpr int BLOCK = WAVES_PER_BLOCK * 64;
constexpr int CHUNK = 64 * 4;       // floats per wave per K-iteration

__global__ __launch_bounds__(BLOCK) void gate_kernel(
    const float* __restrict__ x, const float* __restrict__ W,
    float* __restrict__ out) {
  const int lane = threadIdx.x & 63;
  const int wave = blockIdx.x * WAVES_PER_BLOCK + (threadIdx.x >> 6);
  const int t0 = wave * T_PER_WAVE;  // first token this wave owns

  float acc[T_PER_WAVE][E];
#pragma unroll
  for (int t = 0; t < T_PER_WAVE; t++)
#pragma unroll
    for (int e = 0; e < E; e++) acc[t][e] = 0.f;

  // K loop: per chunk, lane l covers k = c*256 + l*4 .. +3 (coalesced float4)
  for (int c = 0; c < D / CHUNK; c++) {
    const int k = c * CHUNK + lane * 4;
    float4 xv[T_PER_WAVE];
#pragma unroll
    for (int t = 0; t < T_PER_WAVE; t++)
      xv[t] = *(const float4*)(x + (size_t)(t0 + t) * D + k);
#pragma unroll
    for (int e = 0; e < E; e++) {
      const float4 wv = *(const float4*)(W + (size_t)e * D + k);
#pragma unroll
      for (int t = 0; t < T_PER_WAVE; t++) {
        acc[t][e] += xv[t].x * wv.x;
        acc[t][e] += xv[t].y * wv.y;
        acc[t][e] += xv[t].z * wv.z;
        acc[t][e] += xv[t].w * wv.w;
      }
    }
  }

  // Butterfly reduce each of the 32 partials across the 64-lane wave.
#pragma unroll
  for (int t = 0; t < T_PER_WAVE; t++)
#pragma unroll
    for (int e = 0; e < E; e++) {
      float v = acc[t][e];
#pragma unroll
      for (int off = 32; off; off >>= 1) v += __shfl_xor(v, off, 64);
      acc[t][e] = v;
    }

  if (lane == 0) {
    float w1v[T_PER_WAVE], w2v[T_PER_WAVE];
    float i1v[T_PER_WAVE], i2v[T_PER_WAVE];
#pragma unroll
    for (int t = 0; t < T_PER_WAVE; t++) {
      // top-1 (strict > keeps lowest index on ties, matching lax.top_k)
      float m1 = acc[t][0];
      int i1 = 0;
#pragma unroll
      for (int e = 1; e < E; e++)
        if (acc[t][e] > m1) { m1 = acc[t][e]; i1 = e; }
      // top-2 among the rest
      float m2 = -INFINITY;
      int i2 = 0;
#pragma unroll
      for (int e = 0; e < E; e++)
        if (e != i1 && acc[t][e] > m2) { m2 = acc[t][e]; i2 = e; }
      const float s = __expf(m2 - m1);   // exp(l2-l1) <= 1
      const float w1 = 1.f / (1.f + s);
      w1v[t] = w1;
      w2v[t] = 1.f - w1;
      i1v[t] = (float)i1;
      i2v[t] = (float)i2;
    }
    // 4 consecutive tokens -> 8 contiguous floats per output array
    float4* ow = (float4*)(out + 2 * (size_t)t0);
    ow[0] = make_float4(w1v[0], w2v[0], w1v[1], w2v[1]);
    ow[1] = make_float4(w1v[2], w2v[2], w1v[3], w2v[3]);
    float4* oi = (float4*)(out + 2 * (size_t)NT + 2 * (size_t)t0);
    oi[0] = make_float4(i1v[0], i2v[0], i1v[1], i2v[1]);
    oi[1] = make_float4(i1v[2], i2v[2], i1v[3], i2v[3]);
  }
}

extern "C" void kernel_launch(void* const* d_in, const int* in_sizes, int n_in,
                              void* d_out, int out_size, void* d_ws,
                              size_t ws_size, hipStream_t stream) {
  const float* x = (const float*)d_in[0];
  const float* W = (const float*)d_in[1];
  float* out = (float*)d_out;
  const int blocks = NT / (T_PER_WAVE * WAVES_PER_BLOCK);  // 1024
  gate_kernel<<<blocks, BLOCK, 0, stream>>>(x, W, out);
}